// Round 8
// baseline (234.916 us; speedup 1.0000x reference)
//
#include <hip/hip_runtime.h>
#include <math.h>

// Problem constants: T=4, V=2, L=3, N=4000, D=256, TEMP=0.5
#define DD 256
#define NV 2
#define NL 3
#define NNODE 4000
// Row table: B-rows (anchors at all 6 (x,y)) then C-rows (cross negatives).
#define NROWS_B 8640
#define NROWS 10800
#define NANCH 1440
// ws layout (floats): [0, NROWS*128) = z as bf16 (NROWS x 256 ushort)
//                     [ACC_OFF, +1440) pos | [+1440, +2880) neg | [+2880] int counter
//                     [WP_OFF, +65536) frag-ordered bf16 W' (131072 ushort)
//                     W' order: [stage][ks][cgg][lane][j] (slice-contiguous)
#define ACC_OFF (10800L * 128)
#define CNT_IDX (ACC_OFF + 2 * NANCH)
#define WP_OFF (ACC_OFF + 2 * NANCH + 4)
#define XPAD 264   // ushorts/row: 528 B stride, 16B-aligned rows
// k_sim wave-tasks: t<2: 2*6*(7 mt)*(24 chunks of 32) = 2016; t>=2: 2*6*2*5 = 120
#define NTASK 2136
#define NBLK_SIM (NTASK / 4)   // 534 blocks, 4 waves each
#define NBLK_PROJ 225          // 675 row-tiles of 16, 3 per block, 1 block/CU

// ROUND 8 = MEASUREMENT ROUND: k_proj is launched 3x (idempotent -> adds
// exactly 2*P to dur_us). Kernel bodies byte-identical to round 7.

typedef __attribute__((ext_vector_type(8))) short short8;
typedef __attribute__((ext_vector_type(4))) float f32x4;

__device__ __forceinline__ unsigned short f2bf(float f) {
  unsigned u = __float_as_uint(f);
  u += 0x7fff + ((u >> 16) & 1);   // RNE
  return (unsigned short)(u >> 16);
}

__device__ __forceinline__ int tb_B(int t) { return (t < 2) ? t * 3600 : 7200 + (t - 2) * 720; }
__device__ __forceinline__ int tb_C(int t) { return (t < 2) ? t * 900 : 1800 + (t - 2) * 180; }
__device__ __forceinline__ int anch_base(int t, int vl) {
  return ((t < 2) ? t * 600 : 1200 + (t - 2) * 120) + vl * ((t < 2) ? 100 : 20);
}

// Map flat row id u -> source offset (floats) in E. Wave-uniform.
__device__ __forceinline__ long row_src(int u, const int* __restrict__ ip,
                                        const int* __restrict__ ir,
                                        const int* __restrict__ npg,
                                        const int* __restrict__ nrg) {
  int t, x, y, node;
  if (u < NROWS_B) {
    int S, u2;
    if (u < 7200) { t = u / 3600; u2 = u - t * 3600; S = 100; }
    else { int w = u - 7200; t = 2 + w / 720; u2 = w % 720; S = 20; }
    int s = u2 % S; int t1 = u2 / S;
    int l = t1 % NL; int t2 = t1 / NL;
    int v = t2 % NV; int xy = t2 / NV;
    x = xy / NL; y = xy % NL;
    if (t < 2) node = ip[((t * NV + v) * NL + l) * 100 + s];
    else       node = ir[(((t - 2) * NV + v) * NL + l) * 20 + s];
  } else {
    int w = u - NROWS_B;
    int K, u2;
    if (w < 1800) { t = w / 900; u2 = w % 900; K = 50; }
    else { int w2 = w - 1800; t = 2 + w2 / 180; u2 = w2 % 180; K = 10; }
    int k = u2 % K; int t1 = u2 / K;
    int l = t1 % NL; int t2 = t1 / NL;
    int v = t2 % NV; int o = t2 / NV;
    if (t < 2) node = npg[(((t * NV + v) * NL + l) * 3 + o) * 50 + k];
    else       node = nrg[((((t - 2) * NV + v) * NL + l) * 3 + o) * 10 + k];
    int ot = (o < t) ? o : o + 1;
    t = ot; x = v; y = l;
  }
  return ((((long)t * NV + x) * NL + y) * NNODE + node) * DD;
}

// K-1: build frag-ordered bf16 W' ([stage][ks][cgg][lane][8]) and zero accumulators.
__global__ __launch_bounds__(256) void k_prep(const float* __restrict__ W1,
                                              const float* __restrict__ W2,
                                              float* __restrict__ ws) {
  int tid = blockIdx.x * 256 + threadIdx.x;   // grid 64 -> 16384 threads
  if (tid < 2 * NANCH + 4) ws[ACC_OFF + tid] = 0.0f;
  int st = tid >> 13, ks = (tid >> 10) & 7, cgg = (tid >> 6) & 15, lane = tid & 63;
  const float* W = st ? W2 : W1;
  int col = cgg * 16 + (lane & 15);
  int k0 = ks * 32 + (lane >> 4) * 8;
  unsigned short v[8] __attribute__((aligned(16)));
#pragma unroll
  for (int j = 0; j < 8; ++j) v[j] = f2bf(W[col * DD + k0 + j]);
  unsigned short* wp = (unsigned short*)(ws + WP_OFF);
  *(uint4*)(wp + (long)tid * 8) = *(const uint4*)v;
}

// K1 v6: persistent-B MFMA projection (unchanged from round 7).
__global__ __launch_bounds__(512, 2) void k_proj(const float* __restrict__ E,
                                                 const float* __restrict__ b1,
                                                 const float* __restrict__ b2,
                                                 const int* __restrict__ ip,
                                                 const int* __restrict__ ir,
                                                 const int* __restrict__ npg,
                                                 const int* __restrict__ nrg,
                                                 float* __restrict__ ws) {
  __shared__ unsigned short Xs[16][XPAD];
  __shared__ unsigned short Hs[16][XPAD];
  __shared__ float ssbuf[8][16];
  const int tid = threadIdx.x;
  const int wv = tid >> 6, l64 = tid & 63;
  const int quad = l64 >> 4, l15 = l64 & 15;
  const int cb = wv * 32;
  const unsigned short* wp = (const unsigned short*)(ws + WP_OFF);
  unsigned short* zb = (unsigned short*)ws;

  // ---- prologue: load this wave's 32 B-frags into registers ----
  short8 bfr[2][8][2];
#pragma unroll
  for (int st = 0; st < 2; ++st)
#pragma unroll
    for (int ks = 0; ks < 8; ++ks)
#pragma unroll
      for (int cg = 0; cg < 2; ++cg)
        bfr[st][ks][cg] = *(const short8*)(
            wp + ((long)(((st * 8 + ks) * 16 + (wv * 2 + cg)) * 64 + l64)) * 8);

  float bv1[2], bv2[2];
#pragma unroll
  for (int cg = 0; cg < 2; ++cg) {
    bv1[cg] = b1[cb + cg * 16 + l15];
    bv2[cg] = b2[cb + cg * 16 + l15];
  }

  for (int it = 0; it < 3; ++it) {
    int rt = blockIdx.x + it * NBLK_PROJ;      // 0..674
    int u0 = rt * 16;

#pragma unroll
    for (int i = 0; i < 2; ++i) {
      int r = wv * 2 + i;
      long src = row_src(u0 + r, ip, ir, npg, nrg);   // wave-uniform
      float4 val = *(const float4*)(E + src + l64 * 4);
      unsigned short h[4] __attribute__((aligned(8)));
      h[0] = f2bf(val.x); h[1] = f2bf(val.y); h[2] = f2bf(val.z); h[3] = f2bf(val.w);
      *(uint2*)(&Xs[r][l64 * 4]) = *(const uint2*)h;
    }
    __syncthreads();

    // ---- stage 1: H = relu(X @ W1^T + b1) ----
    f32x4 acc[2];
#pragma unroll
    for (int cg = 0; cg < 2; ++cg) acc[cg] = (f32x4){bv1[cg], bv1[cg], bv1[cg], bv1[cg]};
#pragma unroll
    for (int ks = 0; ks < 8; ++ks) {
      short8 a = *(const short8*)(&Xs[l15][ks * 32 + quad * 8]);
#pragma unroll
      for (int cg = 0; cg < 2; ++cg)
        acc[cg] = __builtin_amdgcn_mfma_f32_16x16x32_bf16(a, bfr[0][ks][cg], acc[cg], 0, 0, 0);
    }
#pragma unroll
    for (int cg = 0; cg < 2; ++cg) {
      int col = cb + cg * 16 + l15;
#pragma unroll
      for (int reg = 0; reg < 4; ++reg)            // C/D: col=lane&15, row=quad*4+reg
        Hs[quad * 4 + reg][col] = f2bf(fmaxf(acc[cg][reg], 0.0f));
    }
    __syncthreads();

    // ---- stage 2: Z = H @ W2^T + b2 ----
#pragma unroll
    for (int cg = 0; cg < 2; ++cg) acc[cg] = (f32x4){bv2[cg], bv2[cg], bv2[cg], bv2[cg]};
#pragma unroll
    for (int ks = 0; ks < 8; ++ks) {
      short8 a = *(const short8*)(&Hs[l15][ks * 32 + quad * 8]);
#pragma unroll
      for (int cg = 0; cg < 2; ++cg)
        acc[cg] = __builtin_amdgcn_mfma_f32_16x16x32_bf16(a, bfr[1][ks][cg], acc[cg], 0, 0, 0);
    }

    // ---- normalize (fp32, cross-wave partials) + store bf16 z ----
    float ss[4];
#pragma unroll
    for (int reg = 0; reg < 4; ++reg)
      ss[reg] = fmaf(acc[0][reg], acc[0][reg], acc[1][reg] * acc[1][reg]);
#pragma unroll
    for (int m = 1; m < 16; m <<= 1) {
#pragma unroll
      for (int reg = 0; reg < 4; ++reg) ss[reg] += __shfl_xor(ss[reg], m, 64);
    }
    if (l15 == 0) {
#pragma unroll
      for (int reg = 0; reg < 4; ++reg) ssbuf[wv][quad * 4 + reg] = ss[reg];
    }
    __syncthreads();
#pragma unroll
    for (int reg = 0; reg < 4; ++reg) {
      int row = quad * 4 + reg;
      float tot = 0.f;
#pragma unroll
      for (int w2 = 0; w2 < 8; ++w2) tot += ssbuf[w2][row];
      float sc = 1.0f / fmaxf(sqrtf(tot), 1e-12f);
#pragma unroll
      for (int cg = 0; cg < 2; ++cg)
        zb[(long)(u0 + row) * DD + cb + cg * 16 + l15] = f2bf(acc[cg][reg] * sc);
    }
    __syncthreads();   // protect Xs/Hs/ssbuf before next tile overwrites
  }
}

// K2: fused sims + loss (unchanged from round 7).
__global__ __launch_bounds__(256) void k_sim(float* __restrict__ ws,
                                             float* __restrict__ out) {
  __shared__ float red[256];
  __shared__ int lastFlag;
  const unsigned short* zb = (const unsigned short*)ws;
  float* posG = ws + ACC_OFF;
  float* negG = ws + ACC_OFF + NANCH;
  int* cnt = (int*)(ws + CNT_IDX);

  const int tid = threadIdx.x;
  const int wv = tid >> 6, l64 = tid & 63;
  const int quad = l64 >> 4, l15 = l64 & 15;
  const int task = blockIdx.x * 4 + wv;

  int t, vl, mt, c;
  if (task < 2016) { t = task / 1008; int r = task % 1008;
                     vl = r / 168; int r2 = r % 168; mt = r2 / 24; c = r2 % 24; }
  else { int q = task - 2016; t = 2 + q / 60; int r2 = q % 60;
         vl = r2 / 10; int r3 = r2 % 10; mt = r3 / 5; c = r3 % 5; }
  const int v = vl / NL, l = vl % NL;
  const int S = (t < 2) ? 100 : 20, K = (t < 2) ? 50 : 10;
  const int Ptot = 6 * S + 3 * K;              // 750 / 150
  const int ab = anch_base(t, vl);
  const int rowZbase = tb_B(t) + ((vl * NV + v) * NL + l) * S;

  int am = mt * 16 + l15;
  int amc = (am < S) ? am : (S - 1);
  const unsigned short* abase = zb + (long)(rowZbase + amc) * DD + quad * 8;
  short8 afr[8];
#pragma unroll
  for (int ks = 0; ks < 8; ++ks) afr[ks] = *(const short8*)(abase + ks * 32);

  float negAcc[4] = {0.f, 0.f, 0.f, 0.f};
#pragma unroll
  for (int nt = 0; nt < 2; ++nt) {
    int qg = c * 32 + nt * 16 + l15;
    bool vq = (qg < Ptot);
    int qc = vq ? qg : 0;
    int rowb, xy = -1, j = -1;
    if (qc < 6 * S) {
      xy = qc / S; j = qc - xy * S;
      rowb = tb_B(t) + ((xy * NV + v) * NL + l) * S + j;
    } else {
      int q2 = qc - 6 * S; int o = q2 / K, k2 = q2 - o * K;
      rowb = NROWS_B + tb_C(t) + ((o * NV + v) * NL + l) * K + k2;
    }
    const unsigned short* bbase = zb + (long)rowb * DD + quad * 8;
    f32x4 acc = {0.f, 0.f, 0.f, 0.f};
#pragma unroll
    for (int ks = 0; ks < 8; ++ks) {
      short8 bfr2 = *(const short8*)(bbase + ks * 32);
      acc = __builtin_amdgcn_mfma_f32_16x16x32_bf16(afr[ks], bfr2, acc, 0, 0, 0);
    }
    // element (row = mt*16+quad*4+r, col = qg)
#pragma unroll
    for (int r = 0; r < 4; ++r) {
      int a = mt * 16 + quad * 4 + r;
      if (!vq || a >= S) continue;
      float e = expf(2.0f * acc[r]);
      if (xy >= 0) {
        if (xy == vl) { if (j != a) negAcc[r] += e; }
        else if (j == a) atomicAdd(&posG[ab + a], e);
      } else {
        negAcc[r] += e;
      }
    }
  }
#pragma unroll
  for (int m = 1; m < 16; m <<= 1) {
#pragma unroll
    for (int r = 0; r < 4; ++r) negAcc[r] += __shfl_xor(negAcc[r], m, 64);
  }
  if (l15 == 0) {
#pragma unroll
    for (int r = 0; r < 4; ++r) {
      int a = mt * 16 + quad * 4 + r;
      if (a < S) atomicAdd(&negG[ab + a], negAcc[r]);
    }
  }
  __threadfence();
  __syncthreads();
  if (tid == 0) {
    int old = atomicAdd(cnt, 1);
    lastFlag = (old == NBLK_SIM - 1) ? 1 : 0;
  }
  __syncthreads();
  if (lastFlag) {
    float sum = 0.f;
    for (int i = tid; i < NANCH; i += 256) {
      float p = atomicAdd(&posG[i], 0.0f);   // device-scope coherent read
      float n = atomicAdd(&negG[i], 0.0f);
      sum += -logf(p / (p + n));
    }
    red[tid] = sum;
    __syncthreads();
    for (int s = 128; s > 0; s >>= 1) {
      if (tid < s) red[tid] += red[tid + s];
      __syncthreads();
    }
    if (tid == 0) out[0] = red[0] / (float)NANCH;
  }
}

extern "C" void kernel_launch(void* const* d_in, const int* in_sizes, int n_in,
                              void* d_out, int out_size, void* d_ws, size_t ws_size,
                              hipStream_t stream) {
  const float* E  = (const float*)d_in[0];
  const float* W1 = (const float*)d_in[1];
  const float* b1 = (const float*)d_in[2];
  const float* W2 = (const float*)d_in[3];
  const float* b2 = (const float*)d_in[4];
  const int* ip  = (const int*)d_in[5];
  const int* ir  = (const int*)d_in[6];
  const int* npg = (const int*)d_in[7];
  const int* nrg = (const int*)d_in[8];
  float* ws = (float*)d_ws;   // ~5.9 MB used
  float* out = (float*)d_out;

  hipLaunchKernelGGL(k_prep, dim3(64), dim3(256), 0, stream, W1, W2, ws);
  // MEASUREMENT: k_proj x3 (idempotent). dur_us - R7 = 2 * P exactly.
  hipLaunchKernelGGL(k_proj, dim3(NBLK_PROJ), dim3(512), 0, stream,
                     E, b1, b2, ip, ir, npg, nrg, ws);
  hipLaunchKernelGGL(k_proj, dim3(NBLK_PROJ), dim3(512), 0, stream,
                     E, b1, b2, ip, ir, npg, nrg, ws);
  hipLaunchKernelGGL(k_proj, dim3(NBLK_PROJ), dim3(512), 0, stream,
                     E, b1, b2, ip, ir, npg, nrg, ws);
  hipLaunchKernelGGL(k_sim, dim3(NBLK_SIM), dim3(256), 0, stream, ws, out);
}

// Round 9
// 180.865 us; speedup vs baseline: 1.2989x; 1.2989x over previous
//
#include <hip/hip_runtime.h>
#include <math.h>

// Problem constants: T=4, V=2, L=3, N=4000, D=256, TEMP=0.5
#define DD 256
#define NV 2
#define NL 3
#define NNODE 4000
// Row table: B-rows (anchors at all 6 (x,y)) then C-rows (cross negatives).
#define NROWS_B 8640
#define NROWS 10800
#define NANCH 1440
// ws layout (floats): [0, NROWS*256) = z fp32 | [ACC_OFF,+1440) pos | [+1440,+2880) neg
//                     | [CNT_IDX] spare | [WP_OFF, +65536) frag-ordered bf16 W'
//                     W' order: [stage][ks][cgg][lane][j] (slice-contiguous)
#define ACC_OFF (10800L * 256)
#define CNT_IDX (ACC_OFF + 2 * NANCH)
#define WP_OFF (CNT_IDX + 4)
#define XPAD 264   // ushorts per LDS row in k_proj
#define NBLK_PROJ 225   // 675 row-tiles of 16, 3 per block, 1 block/CU

typedef __attribute__((ext_vector_type(8))) short short8;
typedef __attribute__((ext_vector_type(4))) float f32x4;

__device__ __forceinline__ unsigned short f2bf(float f) {
  unsigned u = __float_as_uint(f);
  u += 0x7fff + ((u >> 16) & 1);   // RNE
  return (unsigned short)(u >> 16);
}

__device__ __forceinline__ int tb_B(int t) { return (t < 2) ? t * 3600 : 7200 + (t - 2) * 720; }
__device__ __forceinline__ int tb_C(int t) { return (t < 2) ? t * 900 : 1800 + (t - 2) * 180; }
__device__ __forceinline__ int anch_base(int t, int vl) {
  return ((t < 2) ? t * 600 : 1200 + (t - 2) * 120) + vl * ((t < 2) ? 100 : 20);
}
__device__ __forceinline__ int zrow_id(int t, int v, int l, int s, int S) {
  int vl = v * NL + l;
  return tb_B(t) + ((vl * NV + v) * NL + l) * S + s;
}

// Map flat row id u -> source offset (floats) in E. Wave-uniform.
__device__ __forceinline__ long row_src(int u, const int* __restrict__ ip,
                                        const int* __restrict__ ir,
                                        const int* __restrict__ npg,
                                        const int* __restrict__ nrg) {
  int t, x, y, node;
  if (u < NROWS_B) {
    int S, u2;
    if (u < 7200) { t = u / 3600; u2 = u - t * 3600; S = 100; }
    else { int w = u - 7200; t = 2 + w / 720; u2 = w % 720; S = 20; }
    int s = u2 % S; int t1 = u2 / S;
    int l = t1 % NL; int t2 = t1 / NL;
    int v = t2 % NV; int xy = t2 / NV;
    x = xy / NL; y = xy % NL;
    if (t < 2) node = ip[((t * NV + v) * NL + l) * 100 + s];
    else       node = ir[(((t - 2) * NV + v) * NL + l) * 20 + s];
  } else {
    int w = u - NROWS_B;
    int K, u2;
    if (w < 1800) { t = w / 900; u2 = w % 900; K = 50; }
    else { int w2 = w - 1800; t = 2 + w2 / 180; u2 = w2 % 180; K = 10; }
    int k = u2 % K; int t1 = u2 / K;
    int l = t1 % NL; int t2 = t1 / NL;
    int v = t2 % NV; int o = t2 / NV;
    if (t < 2) node = npg[(((t * NV + v) * NL + l) * 3 + o) * 50 + k];
    else       node = nrg[((((t - 2) * NV + v) * NL + l) * 3 + o) * 10 + k];
    int ot = (o < t) ? o : o + 1;
    t = ot; x = v; y = l;
  }
  return ((((long)t * NV + x) * NL + y) * NNODE + node) * DD;
}

// K-1: build frag-ordered bf16 W' ([stage][ks][cgg][lane][8]) and zero accumulators.
__global__ __launch_bounds__(256) void k_prep(const float* __restrict__ W1,
                                              const float* __restrict__ W2,
                                              float* __restrict__ ws) {
  int tid = blockIdx.x * 256 + threadIdx.x;   // grid 64 -> 16384 threads
  if (tid < 2 * NANCH + 4) ws[ACC_OFF + tid] = 0.0f;
  int st = tid >> 13, ks = (tid >> 10) & 7, cgg = (tid >> 6) & 15, lane = tid & 63;
  const float* W = st ? W2 : W1;
  int col = cgg * 16 + (lane & 15);
  int k0 = ks * 32 + (lane >> 4) * 8;
  unsigned short v[8] __attribute__((aligned(16)));
#pragma unroll
  for (int j = 0; j < 8; ++j) v[j] = f2bf(W[col * DD + k0 + j]);
  unsigned short* wp = (unsigned short*)(ws + WP_OFF);
  *(uint4*)(wp + (long)tid * 8) = *(const uint4*)v;
}

// K1 v7: persistent-B MFMA projection (v6 structure, measured ~15 us),
// now storing z as fp32 for the proven split sims kernels.
__global__ __launch_bounds__(512, 2) void k_proj(const float* __restrict__ E,
                                                 const float* __restrict__ b1,
                                                 const float* __restrict__ b2,
                                                 const int* __restrict__ ip,
                                                 const int* __restrict__ ir,
                                                 const int* __restrict__ npg,
                                                 const int* __restrict__ nrg,
                                                 float* __restrict__ ws) {
  __shared__ unsigned short Xs[16][XPAD];
  __shared__ unsigned short Hs[16][XPAD];
  __shared__ float ssbuf[8][16];
  const int tid = threadIdx.x;
  const int wv = tid >> 6, l64 = tid & 63;
  const int quad = l64 >> 4, l15 = l64 & 15;
  const int cb = wv * 32;
  const unsigned short* wp = (const unsigned short*)(ws + WP_OFF);

  // ---- prologue: load this wave's 32 B-frags into registers ----
  short8 bfr[2][8][2];
#pragma unroll
  for (int st = 0; st < 2; ++st)
#pragma unroll
    for (int ks = 0; ks < 8; ++ks)
#pragma unroll
      for (int cg = 0; cg < 2; ++cg)
        bfr[st][ks][cg] = *(const short8*)(
            wp + ((long)(((st * 8 + ks) * 16 + (wv * 2 + cg)) * 64 + l64)) * 8);

  float bv1[2], bv2[2];
#pragma unroll
  for (int cg = 0; cg < 2; ++cg) {
    bv1[cg] = b1[cb + cg * 16 + l15];
    bv2[cg] = b2[cb + cg * 16 + l15];
  }

  for (int it = 0; it < 3; ++it) {
    int rt = blockIdx.x + it * NBLK_PROJ;      // 0..674
    int u0 = rt * 16;

#pragma unroll
    for (int i = 0; i < 2; ++i) {
      int r = wv * 2 + i;
      long src = row_src(u0 + r, ip, ir, npg, nrg);   // wave-uniform
      float4 val = *(const float4*)(E + src + l64 * 4);
      unsigned short h[4] __attribute__((aligned(8)));
      h[0] = f2bf(val.x); h[1] = f2bf(val.y); h[2] = f2bf(val.z); h[3] = f2bf(val.w);
      *(uint2*)(&Xs[r][l64 * 4]) = *(const uint2*)h;
    }
    __syncthreads();

    // ---- stage 1: H = relu(X @ W1^T + b1) ----
    f32x4 acc[2];
#pragma unroll
    for (int cg = 0; cg < 2; ++cg) acc[cg] = (f32x4){bv1[cg], bv1[cg], bv1[cg], bv1[cg]};
#pragma unroll
    for (int ks = 0; ks < 8; ++ks) {
      short8 a = *(const short8*)(&Xs[l15][ks * 32 + quad * 8]);
#pragma unroll
      for (int cg = 0; cg < 2; ++cg)
        acc[cg] = __builtin_amdgcn_mfma_f32_16x16x32_bf16(a, bfr[0][ks][cg], acc[cg], 0, 0, 0);
    }
#pragma unroll
    for (int cg = 0; cg < 2; ++cg) {
      int col = cb + cg * 16 + l15;
#pragma unroll
      for (int reg = 0; reg < 4; ++reg)            // C/D: col=lane&15, row=quad*4+reg
        Hs[quad * 4 + reg][col] = f2bf(fmaxf(acc[cg][reg], 0.0f));
    }
    __syncthreads();

    // ---- stage 2: Z = H @ W2^T + b2 ----
#pragma unroll
    for (int cg = 0; cg < 2; ++cg) acc[cg] = (f32x4){bv2[cg], bv2[cg], bv2[cg], bv2[cg]};
#pragma unroll
    for (int ks = 0; ks < 8; ++ks) {
      short8 a = *(const short8*)(&Hs[l15][ks * 32 + quad * 8]);
#pragma unroll
      for (int cg = 0; cg < 2; ++cg)
        acc[cg] = __builtin_amdgcn_mfma_f32_16x16x32_bf16(a, bfr[1][ks][cg], acc[cg], 0, 0, 0);
    }

    // ---- normalize (fp32, cross-wave partials) + store fp32 z ----
    float ss[4];
#pragma unroll
    for (int reg = 0; reg < 4; ++reg)
      ss[reg] = fmaf(acc[0][reg], acc[0][reg], acc[1][reg] * acc[1][reg]);
#pragma unroll
    for (int m = 1; m < 16; m <<= 1) {
#pragma unroll
      for (int reg = 0; reg < 4; ++reg) ss[reg] += __shfl_xor(ss[reg], m, 64);
    }
    if (l15 == 0) {
#pragma unroll
      for (int reg = 0; reg < 4; ++reg) ssbuf[wv][quad * 4 + reg] = ss[reg];
    }
    __syncthreads();
#pragma unroll
    for (int reg = 0; reg < 4; ++reg) {
      int row = quad * 4 + reg;
      float tot = 0.f;
#pragma unroll
      for (int w2 = 0; w2 < 8; ++w2) tot += ssbuf[w2][row];
      float sc = 1.0f / fmaxf(sqrtf(tot), 1e-12f);
#pragma unroll
      for (int cg = 0; cg < 2; ++cg)
        ws[(long)(u0 + row) * DD + cb + cg * 16 + l15] = acc[cg][reg] * sc;
    }
    __syncthreads();   // protect Xs/Hs/ssbuf before next tile overwrites
  }
}

// K2: per (t,vl,xy) grid 144. 4 lanes per dot; global atomicAdd into pos.
// (R2/R3-proven body, verbatim.)
__global__ __launch_bounds__(256) void k_pos(float* __restrict__ ws) {
  const int b = blockIdx.x;
  const int t = b / 36, r = b % 36, vl = r / 6, xy = r % 6;
  if (xy == vl) return;
  const int v = vl / NL, l = vl % NL;
  const int S = (t < 2) ? 100 : 20;
  const int tid = threadIdx.x;
  const int sub = tid & 3;
  const int ab = anch_base(t, vl);
  for (int s0 = 0; s0 < S; s0 += 64) {
    int s = s0 + (tid >> 2);
    if (s >= S) break;
    const float4* za = (const float4*)(ws + (long)zrow_id(t, v, l, s, S) * DD);
    const float4* pa = (const float4*)(ws + (long)(tb_B(t) + ((xy * NV + v) * NL + l) * S + s) * DD);
    float d = 0.0f;
#pragma unroll
    for (int i = 0; i < 16; ++i) {
      float4 a = za[sub + 4 * i];
      float4 bb = pa[sub + 4 * i];
      d = fmaf(a.x, bb.x, d); d = fmaf(a.y, bb.y, d);
      d = fmaf(a.z, bb.z, d); d = fmaf(a.w, bb.w, d);
    }
    d += __shfl_xor(d, 1, 4);
    d += __shfl_xor(d, 2, 4);
    if (sub == 0) atomicAdd(&ws[ACC_OFF + ab + s], expf(2.0f * d));
  }
}

// K3: grid 228 = (t, vl, anchor-half, partner-chunk-32). (R2/R3-proven body.)
#define ZPAD2 260
__global__ __launch_bounds__(256) void k_neg(float* __restrict__ ws) {
  __shared__ float Zt[64][ZPAD2];
  __shared__ float Pt[32][ZPAD2];
  const int b = blockIdx.x;
  int t, vl, c, A0, A;
  if (b < 192) { t = b / 96; int r = b % 96; vl = r / 16; int w = r % 16;
                 A0 = (w / 8) * 50; A = 50; c = w % 8; }
  else { int q = b - 192; t = 2 + q / 18; int r2 = q % 18; vl = r2 / 3;
         c = r2 % 3; A0 = 0; A = 20; }
  const int v = vl / NL, l = vl % NL;
  const int S = (t < 2) ? 100 : 20, K = (t < 2) ? 50 : 10;
  const int Ptot = S + 3 * K;
  const int q0 = c * 32;
  const int pn = min(32, Ptot - q0);
  const int tid = threadIdx.x;
  const int tx = tid & 15, ty = tid >> 4;

  for (int e = tid; e < A * 64; e += 256) {
    int a = e >> 6, kk = (e & 63) * 4;
    long zr = (long)zrow_id(t, v, l, A0 + a, S) * DD;
    *(float4*)(&Zt[a][kk]) = *(const float4*)(ws + zr + kk);
  }
  for (int e = tid; e < pn * 64; e += 256) {
    int p = e >> 6, kk = (e & 63) * 4;
    int qg = q0 + p;
    long row;
    if (qg < S) row = zrow_id(t, v, l, qg, S);
    else { int q2 = qg - S; int o = q2 / K, k2 = q2 % K;
           row = NROWS_B + tb_C(t) + ((o * NV + v) * NL + l) * K + k2; }
    *(float4*)(&Pt[p][kk]) = *(const float4*)(ws + row * DD + kk);
  }
  __syncthreads();

  float acc[4][2];
#pragma unroll
  for (int i = 0; i < 4; ++i) { acc[i][0] = 0.f; acc[i][1] = 0.f; }

  for (int k0 = 0; k0 < DD; k0 += 8) {
    float4 zr0[4], zr1[4];
#pragma unroll
    for (int i = 0; i < 4; ++i) {
      zr0[i] = *(const float4*)(&Zt[ty + 16 * i][k0]);
      zr1[i] = *(const float4*)(&Zt[ty + 16 * i][k0 + 4]);
    }
#pragma unroll
    for (int j = 0; j < 2; ++j) {
      float4 p0 = *(const float4*)(&Pt[tx + 16 * j][k0]);
      float4 p1 = *(const float4*)(&Pt[tx + 16 * j][k0 + 4]);
#pragma unroll
      for (int i = 0; i < 4; ++i) {
        float s = acc[i][j];
        s = fmaf(zr0[i].x, p0.x, s); s = fmaf(zr0[i].y, p0.y, s);
        s = fmaf(zr0[i].z, p0.z, s); s = fmaf(zr0[i].w, p0.w, s);
        s = fmaf(zr1[i].x, p1.x, s); s = fmaf(zr1[i].y, p1.y, s);
        s = fmaf(zr1[i].z, p1.z, s); s = fmaf(zr1[i].w, p1.w, s);
        acc[i][j] = s;
      }
    }
  }

#pragma unroll
  for (int i = 0; i < 4; ++i) {
    int a = ty + 16 * i;
    float sum = 0.0f;
    if (a < A) {
      int sg = A0 + a;
#pragma unroll
      for (int j = 0; j < 2; ++j) {
        int qg = q0 + tx + 16 * j;
        if (qg < Ptot && !(qg < S && qg == sg)) sum += expf(2.0f * acc[i][j]);
      }
    }
    for (int o = 8; o > 0; o >>= 1) sum += __shfl_xor(sum, o, 16);
    if (a < A && tx == 0)
      atomicAdd(&ws[ACC_OFF + NANCH + anch_base(t, vl) + A0 + a], sum);
  }
}

// K4: loss = mean over anchors of -log(pos/(pos+neg))
__global__ __launch_bounds__(256) void k_fin(const float* __restrict__ ws,
                                             float* __restrict__ out) {
  __shared__ float red[256];
  const int tid = threadIdx.x;
  float sum = 0.0f;
  for (int i = tid; i < NANCH; i += 256) {
    float p = ws[ACC_OFF + i];
    float n = ws[ACC_OFF + NANCH + i];
    sum += -logf(p / (p + n));
  }
  red[tid] = sum;
  __syncthreads();
  for (int s = 128; s > 0; s >>= 1) {
    if (tid < s) red[tid] += red[tid + s];
    __syncthreads();
  }
  if (tid == 0) out[0] = red[0] / (float)NANCH;
}

extern "C" void kernel_launch(void* const* d_in, const int* in_sizes, int n_in,
                              void* d_out, int out_size, void* d_ws, size_t ws_size,
                              hipStream_t stream) {
  const float* E  = (const float*)d_in[0];
  const float* W1 = (const float*)d_in[1];
  const float* b1 = (const float*)d_in[2];
  const float* W2 = (const float*)d_in[3];
  const float* b2 = (const float*)d_in[4];
  const int* ip  = (const int*)d_in[5];
  const int* ir  = (const int*)d_in[6];
  const int* npg = (const int*)d_in[7];
  const int* nrg = (const int*)d_in[8];
  float* ws = (float*)d_ws;   // ~11.6 MB: z fp32 + acc + W' bf16
  float* out = (float*)d_out;

  hipLaunchKernelGGL(k_prep, dim3(64), dim3(256), 0, stream, W1, W2, ws);
  hipLaunchKernelGGL(k_proj, dim3(NBLK_PROJ), dim3(512), 0, stream,
                     E, b1, b2, ip, ir, npg, nrg, ws);
  hipLaunchKernelGGL(k_pos, dim3(144), dim3(256), 0, stream, ws);
  hipLaunchKernelGGL(k_neg, dim3(228), dim3(256), 0, stream, ws);
  hipLaunchKernelGGL(k_fin, dim3(1), dim3(256), 0, stream, ws, out);
}